// Round 1
// baseline (1184.095 us; speedup 1.0000x reference)
//
#include <hip/hip_runtime.h>

#define NB 131072
#define ND 512
#define NK 64
#define NCB 1024

// ---------------------------------------------------------------------------
// Precompute: C_dec[c][d] = sum_k cb[c,k] * U[d,k]   (decoded codebook, 2 MB)
//             c_sq[c]     = ||cb[c]||^2
// Each block handles one half-row-block of C_dec; c is block-uniform so the
// codebook row goes through the scalar pipe.
// ---------------------------------------------------------------------------
__global__ __launch_bounds__(256) void vq_precompute(
    const float* __restrict__ U, const float* __restrict__ cb,
    float* __restrict__ C_dec, float* __restrict__ c_sq)
{
    int t = blockIdx.x * 256 + threadIdx.x;   // 0 .. NCB*ND-1
    int c = t >> 9;                           // uniform within block
    int d = t & (ND - 1);
    const float* __restrict__ crow = cb + (size_t)c * NK;
    const float* __restrict__ urow = U + (size_t)d * NK;
    float a0 = 0.f, a1 = 0.f, a2 = 0.f, a3 = 0.f;
#pragma unroll
    for (int k = 0; k < NK; k += 4) {
        a0 = fmaf(crow[k + 0], urow[k + 0], a0);
        a1 = fmaf(crow[k + 1], urow[k + 1], a1);
        a2 = fmaf(crow[k + 2], urow[k + 2], a2);
        a3 = fmaf(crow[k + 3], urow[k + 3], a3);
    }
    C_dec[t] = (a0 + a1) + (a2 + a3);
    if (d == 0) {
        float s0 = 0.f, s1 = 0.f, s2 = 0.f, s3 = 0.f;
#pragma unroll
        for (int k = 0; k < NK; k += 4) {
            s0 = fmaf(crow[k + 0], crow[k + 0], s0);
            s1 = fmaf(crow[k + 1], crow[k + 1], s1);
            s2 = fmaf(crow[k + 2], crow[k + 2], s2);
            s3 = fmaf(crow[k + 3], crow[k + 3], s3);
        }
        c_sq[c] = (s0 + s1) + (s2 + s3);
    }
}

// ---------------------------------------------------------------------------
// Main kernel: one thread owns one row of x.
//   Phase A: z[64] = x_row @ U          (z in VGPRs, U rows via scalar pipe)
//   Phase B: argmin_j ||z - cb[j]||^2 = argmin_j (c_sq[j] - 2 z.cb[j])
//            serial ascending scan -> np.argmin first-min tie-break for free
//   Phase C: write x_recon (gather from C_dec), z, z_q, idx(float)
// USE_WS=0 is a correctness fallback if d_ws is too small (no C_dec/c_sq).
// ---------------------------------------------------------------------------
template <int USE_WS>
__global__ __launch_bounds__(256, 2) void vq_main(
    const float* __restrict__ x, const float* __restrict__ U,
    const float* __restrict__ cb, const float* __restrict__ c_sq,
    const float* __restrict__ C_dec, float* __restrict__ out)
{
    const int r = blockIdx.x * 256 + threadIdx.x;   // row index
    const float4* __restrict__ x4 = (const float4*)(x + (size_t)r * ND);

    float z[NK];
#pragma unroll
    for (int j = 0; j < NK; ++j) z[j] = 0.f;

    // ---- Phase A: z = x_row @ U ----
    for (int k4 = 0; k4 < ND / 4; ++k4) {
        float4 xv = x4[k4];
        const float* __restrict__ u = U + (size_t)(4 * k4) * NK;
#pragma unroll
        for (int j = 0; j < NK; ++j) z[j] = fmaf(u[j], xv.x, z[j]);
        u += NK;
#pragma unroll
        for (int j = 0; j < NK; ++j) z[j] = fmaf(u[j], xv.y, z[j]);
        u += NK;
#pragma unroll
        for (int j = 0; j < NK; ++j) z[j] = fmaf(u[j], xv.z, z[j]);
        u += NK;
#pragma unroll
        for (int j = 0; j < NK; ++j) z[j] = fmaf(u[j], xv.w, z[j]);
    }

    // ---- Phase B: argmin over codebook ----
    float best = 3.4e38f;
    int bidx = 0;
    for (int j = 0; j < NCB; ++j) {
        const float* __restrict__ c = cb + (size_t)j * NK;
        float a0 = 0.f, a1 = 0.f, a2 = 0.f, a3 = 0.f;
        float s0 = 0.f, s1 = 0.f, s2 = 0.f, s3 = 0.f;
#pragma unroll
        for (int k = 0; k < NK; k += 4) {
            a0 = fmaf(z[k + 0], c[k + 0], a0);
            a1 = fmaf(z[k + 1], c[k + 1], a1);
            a2 = fmaf(z[k + 2], c[k + 2], a2);
            a3 = fmaf(z[k + 3], c[k + 3], a3);
            if (!USE_WS) {   // inline ||c||^2 when no workspace
                s0 = fmaf(c[k + 0], c[k + 0], s0);
                s1 = fmaf(c[k + 1], c[k + 1], s1);
                s2 = fmaf(c[k + 2], c[k + 2], s2);
                s3 = fmaf(c[k + 3], c[k + 3], s3);
            }
        }
        float dot = (a0 + a1) + (a2 + a3);
        float csq = USE_WS ? c_sq[j] : ((s0 + s1) + (s2 + s3));
        float dist = fmaf(-2.f, dot, csq);
        if (dist < best) { best = dist; bidx = j; }   // strict < == first-min
    }

    // ---- Phase C: outputs ----
    float* __restrict__ out_recon = out;                              // B*D
    float* __restrict__ out_z   = out + (size_t)NB * ND;              // B*K
    float* __restrict__ out_zq  = out_z + (size_t)NB * NK;            // B*K
    float* __restrict__ out_idx = out_zq + (size_t)NB * NK;           // B

    // z
    float4* __restrict__ oz = (float4*)(out_z + (size_t)r * NK);
#pragma unroll
    for (int q = 0; q < NK / 4; ++q)
        oz[q] = make_float4(z[4 * q], z[4 * q + 1], z[4 * q + 2], z[4 * q + 3]);

    // z_q (gather codebook row; keep values for fallback decode)
    float zq[NK];
    const float4* __restrict__ crow4 = (const float4*)(cb + (size_t)bidx * NK);
    float4* __restrict__ ozq = (float4*)(out_zq + (size_t)r * NK);
#pragma unroll
    for (int q = 0; q < NK / 4; ++q) {
        float4 v = crow4[q];
        ozq[q] = v;
        zq[4 * q] = v.x; zq[4 * q + 1] = v.y; zq[4 * q + 2] = v.z; zq[4 * q + 3] = v.w;
    }

    // indices (output buffer is float32)
    out_idx[r] = (float)bidx;

    // x_recon
    float4* __restrict__ orc = (float4*)(out_recon + (size_t)r * ND);
    if (USE_WS) {
        const float4* __restrict__ drow = (const float4*)(C_dec + (size_t)bidx * ND);
#pragma unroll 4
        for (int q = 0; q < ND / 4; ++q) orc[q] = drow[q];
    } else {
        for (int d = 0; d < ND; d += 4) {
            float r0 = 0.f, r1 = 0.f, r2 = 0.f, r3 = 0.f;
            const float* __restrict__ u0 = U + (size_t)(d + 0) * NK;
            const float* __restrict__ u1 = U + (size_t)(d + 1) * NK;
            const float* __restrict__ u2 = U + (size_t)(d + 2) * NK;
            const float* __restrict__ u3 = U + (size_t)(d + 3) * NK;
#pragma unroll
            for (int k = 0; k < NK; ++k) {
                r0 = fmaf(zq[k], u0[k], r0);
                r1 = fmaf(zq[k], u1[k], r1);
                r2 = fmaf(zq[k], u2[k], r2);
                r3 = fmaf(zq[k], u3[k], r3);
            }
            orc[d / 4] = make_float4(r0, r1, r2, r3);
        }
    }
}

extern "C" void kernel_launch(void* const* d_in, const int* in_sizes, int n_in,
                              void* d_out, int out_size, void* d_ws, size_t ws_size,
                              hipStream_t stream) {
    const float* x  = (const float*)d_in[0];
    const float* U  = (const float*)d_in[1];
    const float* cb = (const float*)d_in[2];
    float* out = (float*)d_out;

    const size_t need = (size_t)NCB * ND * sizeof(float) + NCB * sizeof(float);
    if (ws_size >= need) {
        float* C_dec = (float*)d_ws;
        float* c_sq  = C_dec + (size_t)NCB * ND;
        vq_precompute<<<(NCB * ND) / 256, 256, 0, stream>>>(U, cb, C_dec, c_sq);
        vq_main<1><<<NB / 256, 256, 0, stream>>>(x, U, cb, c_sq, C_dec, out);
    } else {
        vq_main<0><<<NB / 256, 256, 0, stream>>>(x, U, cb, nullptr, nullptr, out);
    }
}